// Round 3
// baseline (529.918 us; speedup 1.0000x reference)
//
#include <hip/hip_runtime.h>

typedef float  f32x4  __attribute__((ext_vector_type(4)));
typedef __bf16 bf16x8 __attribute__((ext_vector_type(8)));
typedef __bf16 bf16x4 __attribute__((ext_vector_type(4)));

#define DEVFN static __device__ __forceinline__

constexpr int BB = 2, SS = 4096, DD = 1024;
constexpr int MROWS = BB * SS; // 8192

// ---------------- workspace layout (bytes) ----------------
constexpr size_t SZ_QK   = (size_t)MROWS * DD * 2;
constexpr size_t SZ_VT   = (size_t)BB * DD * SS * 2;
constexpr size_t SZ_ATTN = (size_t)BB * SS * SS * 2;
constexpr size_t SZ_S    = (size_t)BB * SS * SS * 4;
constexpr size_t SZ_W    = (size_t)DD * DD * 2;

constexpr size_t O_VT   = 0;
constexpr size_t O_ATTN = O_VT + SZ_VT;
constexpr size_t O_QH   = O_ATTN;
constexpr size_t O_QL   = O_QH + SZ_QK;
constexpr size_t O_KH   = O_QL + SZ_QK;
constexpr size_t O_KL   = O_KH + SZ_QK;
constexpr size_t O_S    = O_ATTN + SZ_ATTN;
constexpr size_t O_XH   = O_S;
constexpr size_t O_XL   = O_XH + SZ_QK;
constexpr size_t O_WQH  = O_XL + SZ_QK;
constexpr size_t O_WQL  = O_WQH + SZ_W;
constexpr size_t O_WKH  = O_WQL + SZ_W;
constexpr size_t O_WKL  = O_WKH + SZ_W;
constexpr size_t O_WVH  = O_WKL + SZ_W;
constexpr size_t O_WVL  = O_WVH + SZ_W;
constexpr size_t WS_NEEDED = SZ_VT + SZ_ATTN + SZ_S;

// ---------------- helpers ----------------
DEVFN f32x4 mfma16x16x32(bf16x8 a, bf16x8 b, f32x4 c) {
  return __builtin_amdgcn_mfma_f32_16x16x32_bf16(a, b, c, 0, 0, 0);
}

DEVFN void gld16(const __bf16* g, char* l) {
  __builtin_amdgcn_global_load_lds((const __attribute__((address_space(1))) void*)g,
                                   (__attribute__((address_space(3))) void*)l, 16, 0, 0);
}

// =====================================================================
// 256x256 8-phase GEMM core (B^T layout, K-concatenated 3-segment split).
// Staging schedule (tile u, 2 gld_lds per phase, deadlines >=3 phases):
//   B(u) q0,q1 @ (u-2).ph3 | B(u) q2,q3 @ (u-1).ph0
//   A(u) q0,q2 @ (u-1).ph1 | A(u) q1,q3 @ (u-1).ph2
// Waits: vmcnt(6) end of ph1 (gates A q1,q3 for ph2);
//        vmcnt(4) end of ph3 (gates next tile's ph0 operands).
// Invariant entering tile u: in flight = {A(u)q1, A(u)q3, B(u+1)q0, B(u+1)q1}.
// =====================================================================
struct Segs { const __bf16 *a0, *a1, *a2, *b0, *b1, *b2; };

DEVFN void gemm256_core(Segs s, int NT, char* smem, f32x4 (&acc)[8][4]) {
  const int tid = threadIdx.x, lane = tid & 63, wave = tid >> 6;
  const int wm = wave >> 2, wn = wave & 3;
  // staging: per-lane inverse-swizzled global source offset
  const size_t rk = (size_t)((wave << 3) + (lane >> 3)) * DD +
                    (size_t)((((lane & 7) ^ (lane >> 3)) << 3));
  const int wvoff = wave << 10; // wave-uniform LDS byte base within quarter
  // fragment-read addressing (swizzled)
  const int rbA = (((wm << 7) + (lane & 15)) << 7);
  const int rbB = (((wn << 6) + (lane & 15)) << 7);
  const int cx0 = (((lane >> 4) << 4)) ^ ((lane & 7) << 4);
  const int cx1 = cx0 ^ 64;

  char* LA0 = smem;
  char* LB0 = smem + 32768;
  char* LA1 = smem + 65536;
  char* LB1 = smem + 98304;

  auto stA = [&](int u, int q, char* dst) {
    int uc = (u < NT) ? u : (NT - 1); // tail clamp keeps vmcnt counts uniform
    int sg = uc >> 4;
    const __bf16* p = (sg == 0) ? s.a0 : ((sg == 1) ? s.a1 : s.a2);
    gld16(p + ((size_t)(q << 6)) * DD + ((uc & 15) << 6) + rk, dst + (q << 13) + wvoff);
  };
  auto stB = [&](int u, int q, char* dst) {
    int uc = (u < NT) ? u : (NT - 1);
    int sg = uc >> 4;
    const __bf16* p = (sg == 0) ? s.b0 : ((sg == 1) ? s.b1 : s.b2);
    gld16(p + ((size_t)(q << 6)) * DD + ((uc & 15) << 6) + rk, dst + (q << 13) + wvoff);
  };
  auto rdA = [&](char* l, int m, int cx) { return *(const bf16x8*)(l + rbA + (m << 11) + cx); };
  auto rdB = [&](char* l, int n, int cx) { return *(const bf16x8*)(l + rbB + (n << 11) + cx); };

  // ---- prologue: issue order fixes vmcnt semantics ----
  stB(0, 0, LB0); stB(0, 1, LB0); stB(0, 2, LB0); stB(0, 3, LB0);
  stA(0, 0, LA0); stA(0, 2, LA0); stA(0, 1, LA0); stA(0, 3, LA0);
  stB(1, 0, LB1); stB(1, 1, LB1);
  asm volatile("s_waitcnt vmcnt(4)" ::: "memory");
  __builtin_amdgcn_s_barrier();

  auto tile = [&](char* lA, char* lB, char* lAn, char* lBn, int t) {
    bf16x8 a0[4][2], a1[4][2], b0[2][2], b1[2][2];
    // ---- phase 0: msub0 x nsub0 ----
#pragma unroll
    for (int m = 0; m < 4; ++m) { a0[m][0] = rdA(lA, m, cx0); a0[m][1] = rdA(lA, m, cx1); }
#pragma unroll
    for (int n = 0; n < 2; ++n) { b0[n][0] = rdB(lB, n, cx0); b0[n][1] = rdB(lB, n, cx1); }
    stB(t + 1, 2, lBn); stB(t + 1, 3, lBn);
    __builtin_amdgcn_s_barrier();
    asm volatile("s_waitcnt lgkmcnt(0)" ::: "memory");
    __builtin_amdgcn_s_setprio(1);
#pragma unroll
    for (int m = 0; m < 4; ++m)
#pragma unroll
      for (int n = 0; n < 2; ++n) {
        acc[m][n] = mfma16x16x32(a0[m][0], b0[n][0], acc[m][n]);
        acc[m][n] = mfma16x16x32(a0[m][1], b0[n][1], acc[m][n]);
      }
    __builtin_amdgcn_s_setprio(0);
    __builtin_amdgcn_s_barrier();
    // ---- phase 1: msub0 x nsub1 ----
#pragma unroll
    for (int n = 0; n < 2; ++n) { b1[n][0] = rdB(lB, n + 2, cx0); b1[n][1] = rdB(lB, n + 2, cx1); }
    stA(t + 1, 0, lAn); stA(t + 1, 2, lAn);
    __builtin_amdgcn_s_barrier();
    asm volatile("s_waitcnt lgkmcnt(0)" ::: "memory");
    __builtin_amdgcn_s_setprio(1);
#pragma unroll
    for (int m = 0; m < 4; ++m)
#pragma unroll
      for (int n = 0; n < 2; ++n) {
        acc[m][n + 2] = mfma16x16x32(a0[m][0], b1[n][0], acc[m][n + 2]);
        acc[m][n + 2] = mfma16x16x32(a0[m][1], b1[n][1], acc[m][n + 2]);
      }
    __builtin_amdgcn_s_setprio(0);
    asm volatile("s_waitcnt vmcnt(6)" ::: "memory"); // A(t+1) q1,q3 landed
    __builtin_amdgcn_s_barrier();
    // ---- phase 2: msub1 x nsub0 ----
#pragma unroll
    for (int m = 0; m < 4; ++m) { a1[m][0] = rdA(lA, m + 4, cx0); a1[m][1] = rdA(lA, m + 4, cx1); }
    stA(t + 1, 1, lAn); stA(t + 1, 3, lAn);
    __builtin_amdgcn_s_barrier();
    asm volatile("s_waitcnt lgkmcnt(0)" ::: "memory");
    __builtin_amdgcn_s_setprio(1);
#pragma unroll
    for (int m = 0; m < 4; ++m)
#pragma unroll
      for (int n = 0; n < 2; ++n) {
        acc[m + 4][n] = mfma16x16x32(a1[m][0], b0[n][0], acc[m + 4][n]);
        acc[m + 4][n] = mfma16x16x32(a1[m][1], b0[n][1], acc[m + 4][n]);
      }
    __builtin_amdgcn_s_setprio(0);
    __builtin_amdgcn_s_barrier();
    // ---- phase 3: msub1 x nsub1 ----
    stB(t + 2, 0, lB); stB(t + 2, 1, lB); // into current B buffer (t+2 same parity)
    __builtin_amdgcn_s_barrier();
    __builtin_amdgcn_s_setprio(1);
#pragma unroll
    for (int m = 0; m < 4; ++m)
#pragma unroll
      for (int n = 0; n < 2; ++n) {
        acc[m + 4][n + 2] = mfma16x16x32(a1[m][0], b1[n][0], acc[m + 4][n + 2]);
        acc[m + 4][n + 2] = mfma16x16x32(a1[m][1], b1[n][1], acc[m + 4][n + 2]);
      }
    __builtin_amdgcn_s_setprio(0);
    asm volatile("s_waitcnt vmcnt(4)" ::: "memory"); // next tile ph0 operands landed
    __builtin_amdgcn_s_barrier();
  };

  for (int t = 0; t < NT; t += 2) {
    tile(LA0, LB0, LA1, LB1, t);
    tile(LA1, LB1, LA0, LB0, t + 1);
  }
  asm volatile("s_waitcnt vmcnt(0)" ::: "memory"); // drain tail clamp stages
}

// ---------------- scores = [Qh|Qh|Ql] . [Kh|Kl|Kh]^T, fp32 out ----------------
__global__ __launch_bounds__(512, 2)
void gemm256_scores(const __bf16* __restrict__ Qh, const __bf16* __restrict__ Ql,
                    const __bf16* __restrict__ Kh, const __bf16* __restrict__ Kl,
                    float* __restrict__ Sf) {
  extern __shared__ char smem[];
  const int z = blockIdx.z;
  const size_t zo = (size_t)z * SS * DD;
  const int row0 = blockIdx.y * 256, col0 = blockIdx.x * 256;
  const size_t ra = zo + (size_t)row0 * DD, rb = zo + (size_t)col0 * DD;
  Segs s{Qh + ra, Qh + ra, Ql + ra, Kh + rb, Kl + rb, Kh + rb};
  f32x4 acc[8][4] = {};
  gemm256_core(s, 48, smem, acc);

  float* C = Sf + (size_t)z * SS * SS;
  const int lane = threadIdx.x & 63, wave = threadIdx.x >> 6;
  const int wm = wave >> 2, wn = wave & 3;
#pragma unroll
  for (int m = 0; m < 8; ++m)
#pragma unroll
    for (int n = 0; n < 4; ++n) {
      int col = col0 + wn * 64 + n * 16 + (lane & 15);
      int rowb = row0 + wm * 128 + m * 16 + (lane >> 4) * 4;
#pragma unroll
      for (int j = 0; j < 4; ++j)
        C[(size_t)(rowb + j) * SS + col] = acc[m][n][j];
    }
}

// ---------------- fused Q+K projections, N-concat (grid 8x32 = 256 blocks) -------
__global__ __launch_bounds__(512, 2)
void gemm256_projqk(const __bf16* __restrict__ xh, const __bf16* __restrict__ xl,
                    const __bf16* __restrict__ wqh, const __bf16* __restrict__ wql,
                    const __bf16* __restrict__ wkh, const __bf16* __restrict__ wkl,
                    const float* __restrict__ bq, const float* __restrict__ bk,
                    __bf16* __restrict__ Qh, __bf16* __restrict__ Ql,
                    __bf16* __restrict__ Kh, __bf16* __restrict__ Kl) {
  extern __shared__ char smem[];
  const int row0 = blockIdx.y * 256;
  const int cg = blockIdx.x;          // 0..3 = Q cols, 4..7 = K cols
  const bool isK = cg >= 4;
  const int col0 = (cg & 3) * 256;
  const __bf16* B0 = isK ? wkh : wqh;
  const __bf16* B1 = isK ? wkl : wql;
  const float* bias = isK ? bk : bq;
  __bf16* CH = isK ? Kh : Qh;
  __bf16* CL = isK ? Kl : Ql;

  const size_t ra = (size_t)row0 * DD, rb = (size_t)col0 * DD;
  Segs s{xh + ra, xh + ra, xl + ra, B0 + rb, B1 + rb, B0 + rb};
  f32x4 acc[8][4] = {};
  gemm256_core(s, 48, smem, acc);

  const int lane = threadIdx.x & 63, wave = threadIdx.x >> 6;
  const int wm = wave >> 2, wn = wave & 3;
#pragma unroll
  for (int m = 0; m < 8; ++m)
#pragma unroll
    for (int n = 0; n < 4; ++n) {
      int col = col0 + wn * 64 + n * 16 + (lane & 15);
      float bvv = bias[col];
      int rowb = row0 + wm * 128 + m * 16 + (lane >> 4) * 4;
#pragma unroll
      for (int j = 0; j < 4; ++j) {
        float v = acc[m][n][j] + bvv;
        size_t idx = (size_t)(rowb + j) * DD + col;
        __bf16 h = (__bf16)v;
        CH[idx] = h;
        CL[idx] = (__bf16)(v - (float)h);
      }
    }
}

// ---------------- Vt = Wv . x^T directly (A=Wv [1024][1024], B=xh [8192][1024]) ---
__global__ __launch_bounds__(512, 2)
void gemm256_vt(const __bf16* __restrict__ wvh, const __bf16* __restrict__ xh,
                const float* __restrict__ bvv, __bf16* __restrict__ Vt) {
  extern __shared__ char smem[];
  const int row0 = blockIdx.y * 256;  // d
  const int col0 = blockIdx.x * 256;  // s global (0..8191)
  const size_t ra = (size_t)row0 * DD, rb = (size_t)col0 * DD;
  Segs s{wvh + ra, wvh + ra, wvh + ra, xh + rb, xh + rb, xh + rb};
  f32x4 acc[8][4] = {};
  gemm256_core(s, 16, smem, acc); // single segment, K=1024

  const int lane = threadIdx.x & 63, wave = threadIdx.x >> 6;
  const int wm = wave >> 2, wn = wave & 3;
#pragma unroll
  for (int m = 0; m < 8; ++m)
#pragma unroll
    for (int n = 0; n < 4; ++n) {
      int col = col0 + wn * 64 + n * 16 + (lane & 15);
      int batch = col >> 12, sl = col & 4095;
      int rowb = row0 + wm * 128 + m * 16 + (lane >> 4) * 4;
#pragma unroll
      for (int j = 0; j < 4; ++j) {
        float v = acc[m][n][j] + bvv[rowb + j]; // bias along d (rows)
        Vt[(size_t)batch * DD * SS + (size_t)(rowb + j) * SS + sl] = (__bf16)v;
      }
    }
}

// ---------------- split fp32 -> bf16 hi/lo ----------------
__global__ __launch_bounds__(256)
void split_f32_bf16x2(const float* __restrict__ in, __bf16* __restrict__ hi,
                      __bf16* __restrict__ lo, int n) {
  int stride = gridDim.x * blockDim.x;
  for (int i = blockIdx.x * blockDim.x + threadIdx.x; i * 4 < n; i += stride) {
    f32x4 x = *(const f32x4*)(in + (size_t)i * 4);
    bf16x4 h, l;
#pragma unroll
    for (int e = 0; e < 4; ++e) {
      __bf16 hh = (__bf16)x[e];
      h[e] = hh;
      l[e] = (__bf16)(x[e] - (float)hh);
    }
    *(bf16x4*)(hi + (size_t)i * 4) = h;
    *(bf16x4*)(lo + (size_t)i * 4) = l;
  }
}

// ---------------- legacy 128^2 GEMM for PV (fills machine: 512 blocks) ----------
DEVFN void stage_tile(__bf16* ldsb, const __bf16* gptr, int ld, int tid) {
  char* lb = (char*)ldsb + ((tid >> 6) << 10);
  gld16(gptr, lb);
  gld16(gptr + (size_t)64 * ld, lb + 4096);
}

__global__ __launch_bounds__(256)
void gemm_bt_pv(const __bf16* __restrict__ Ah, const __bf16* __restrict__ Bh,
                float* __restrict__ Cf, int M, int N, int K,
                size_t sAb, size_t sBb, size_t sCb) {
  const int b = blockIdx.z;
  Ah += (size_t)b * sAb; Bh += (size_t)b * sBb;

  __shared__ __bf16 lds[2][128 * 32];

  const int tid = threadIdx.x;
  const int lane = tid & 63, wave = tid >> 6;
  const int wm = (wave >> 1) * 64, wn = (wave & 1) * 64;
  const int row0 = blockIdx.y * 128, col0 = blockIdx.x * 128;
  const int sr = tid >> 2, sc = (tid & 3) * 8;

  const __bf16* gA = Ah + (size_t)(row0 + sr) * K + sc;
  const __bf16* gB = Bh + (size_t)(col0 + sr) * K + sc;

  f32x4 acc[4][4] = {};

  for (int k0 = 0; k0 < K; k0 += 32) {
    __syncthreads();
    stage_tile(lds[0], gA + k0, K, tid);
    stage_tile(lds[1], gB + k0, K, tid);
    __syncthreads();

    const int kg = (lane >> 4) * 8;
    bf16x8 ah[4], bh[4];
#pragma unroll
    for (int m = 0; m < 4; ++m)
      ah[m] = *(const bf16x8*)&lds[0][(wm + m * 16 + (lane & 15)) * 32 + kg];
#pragma unroll
    for (int n = 0; n < 4; ++n)
      bh[n] = *(const bf16x8*)&lds[1][(wn + n * 16 + (lane & 15)) * 32 + kg];
#pragma unroll
    for (int m = 0; m < 4; ++m)
#pragma unroll
      for (int n = 0; n < 4; ++n)
        acc[m][n] = mfma16x16x32(ah[m], bh[n], acc[m][n]);
  }

  Cf += (size_t)b * sCb;
#pragma unroll
  for (int m = 0; m < 4; ++m)
#pragma unroll
    for (int n = 0; n < 4; ++n) {
      int gcol = col0 + wn + n * 16 + (lane & 15);
#pragma unroll
      for (int j = 0; j < 4; ++j) {
        int grow = row0 + wm + m * 16 + (lane >> 4) * 4 + j;
        Cf[(size_t)grow * N + gcol] = acc[m][n][j];
      }
    }
}

// ---------------- softmax + dropout ----------------
__global__ __launch_bounds__(256)
void softmax_dropout(const float* __restrict__ Sf, const float* __restrict__ U,
                     __bf16* __restrict__ P) {
  __shared__ float red[4];
  const size_t row = blockIdx.x;
  const float* s = Sf + row * SS;
  const float* u = U + row * SS;
  __bf16* p = P + row * SS;
  const int tid = threadIdx.x, lane = tid & 63, wave = tid >> 6;

  f32x4 v[4];
  float m = -3.0e38f;
#pragma unroll
  for (int j = 0; j < 4; ++j) {
    v[j] = *(const f32x4*)(s + (size_t)(j * 256 + tid) * 4);
#pragma unroll
    for (int e = 0; e < 4; ++e) m = fmaxf(m, v[j][e]);
  }
#pragma unroll
  for (int o = 32; o > 0; o >>= 1) m = fmaxf(m, __shfl_xor(m, o));
  if (lane == 0) red[wave] = m;
  __syncthreads();
  m = fmaxf(fmaxf(red[0], red[1]), fmaxf(red[2], red[3]));

  float sum = 0.0f;
#pragma unroll
  for (int j = 0; j < 4; ++j)
#pragma unroll
    for (int e = 0; e < 4; ++e) { float ex = __expf(v[j][e] - m); v[j][e] = ex; sum += ex; }
#pragma unroll
  for (int o = 32; o > 0; o >>= 1) sum += __shfl_xor(sum, o);
  __syncthreads();
  if (lane == 0) red[wave] = sum;
  __syncthreads();
  sum = red[0] + red[1] + red[2] + red[3];
  const float scale = 1.25f / sum;

#pragma unroll
  for (int j = 0; j < 4; ++j) {
    f32x4 uu = *(const f32x4*)(u + (size_t)(j * 256 + tid) * 4);
    bf16x4 out;
#pragma unroll
    for (int e = 0; e < 4; ++e)
      out[e] = (__bf16)((uu[e] >= 0.2f) ? v[j][e] * scale : 0.0f);
    *(bf16x4*)(p + (size_t)(j * 256 + tid) * 4) = out;
  }
}

// ---------------- launcher ----------------
extern "C" void kernel_launch(void* const* d_in, const int* in_sizes, int n_in,
                              void* d_out, int out_size, void* d_ws, size_t ws_size,
                              hipStream_t stream) {
  if (ws_size < WS_NEEDED) return;

  const float* x  = (const float*)d_in[0];
  const float* Wq = (const float*)d_in[1];
  const float* bq = (const float*)d_in[2];
  const float* Wk = (const float*)d_in[3];
  const float* bk = (const float*)d_in[4];
  const float* Wv = (const float*)d_in[5];
  const float* bv = (const float*)d_in[6];
  const float* du = (const float*)d_in[7];

  char* ws = (char*)d_ws;
  __bf16* Vt  = (__bf16*)(ws + O_VT);
  __bf16* Pb  = (__bf16*)(ws + O_ATTN);
  __bf16* Qh  = (__bf16*)(ws + O_QH);
  __bf16* Ql  = (__bf16*)(ws + O_QL);
  __bf16* Kh  = (__bf16*)(ws + O_KH);
  __bf16* Kl  = (__bf16*)(ws + O_KL);
  float*  Sf  = (float*) (ws + O_S);
  __bf16* xh  = (__bf16*)(ws + O_XH);
  __bf16* xl  = (__bf16*)(ws + O_XL);
  __bf16* wqh = (__bf16*)(ws + O_WQH);
  __bf16* wql = (__bf16*)(ws + O_WQL);
  __bf16* wkh = (__bf16*)(ws + O_WKH);
  __bf16* wkl = (__bf16*)(ws + O_WKL);
  __bf16* wvh = (__bf16*)(ws + O_WVH);
  __bf16* wvl = (__bf16*)(ws + O_WVL);
  float*  out = (float*)d_out;

  hipFuncSetAttribute((const void*)gemm256_scores,
                      hipFuncAttributeMaxDynamicSharedMemorySize, 131072);
  hipFuncSetAttribute((const void*)gemm256_projqk,
                      hipFuncAttributeMaxDynamicSharedMemorySize, 131072);
  hipFuncSetAttribute((const void*)gemm256_vt,
                      hipFuncAttributeMaxDynamicSharedMemorySize, 131072);

  // 1) splits
  split_f32_bf16x2<<<2048, 256, 0, stream>>>(x,  xh,  xl,  MROWS * DD);
  split_f32_bf16x2<<<256,  256, 0, stream>>>(Wq, wqh, wql, DD * DD);
  split_f32_bf16x2<<<256,  256, 0, stream>>>(Wk, wkh, wkl, DD * DD);
  split_f32_bf16x2<<<256,  256, 0, stream>>>(Wv, wvh, wvl, DD * DD);

  // 2) Q+K projections, N-concat (256 blocks = 1/CU)
  gemm256_projqk<<<dim3(8, MROWS / 256), 512, 131072, stream>>>(
      xh, xl, wqh, wql, wkh, wkl, bq, bk, Qh, Ql, Kh, Kl);

  // 3) Vt = Wv . x^T + bv (direct transposed V, no separate transpose pass)
  gemm256_vt<<<dim3(MROWS / 256, DD / 256), 512, 131072, stream>>>(wvh, xh, bv, Vt);

  // 4) scores = Q K^T (split via K-concat, fp32 out)
  gemm256_scores<<<dim3(SS / 256, SS / 256, BB), 512, 131072, stream>>>(Qh, Ql, Kh, Kl, Sf);

  // 5) softmax + dropout -> attn bf16 (overwrites dead Q/K splits)
  softmax_dropout<<<MROWS, 256, 0, stream>>>(Sf, du, Pb);

  // 6) out = attn @ V (B operand = Vt, K-contiguous)
  gemm_bt_pv<<<dim3(DD / 128, SS / 128, BB), 256, 0, stream>>>(
      Pb, Vt, out, SS, DD, SS,
      (size_t)SS * SS, (size_t)DD * SS, (size_t)SS * DD);
}

// Round 4
// 528.998 us; speedup vs baseline: 1.0017x; 1.0017x over previous
//
#include <hip/hip_runtime.h>

typedef float  f32x4  __attribute__((ext_vector_type(4)));
typedef __bf16 bf16x8 __attribute__((ext_vector_type(8)));
typedef __bf16 bf16x4 __attribute__((ext_vector_type(4)));

#define DEVFN static __device__ __forceinline__

constexpr int BB = 2, SS = 4096, DD = 1024;
constexpr int MROWS = BB * SS; // 8192

// ---------------- workspace layout (bytes) ----------------
constexpr size_t SZ_QK   = (size_t)MROWS * DD * 2;
constexpr size_t SZ_VT   = (size_t)BB * DD * SS * 2;
constexpr size_t SZ_ATTN = (size_t)BB * SS * SS * 2;
constexpr size_t SZ_S    = (size_t)BB * SS * SS * 4;
constexpr size_t SZ_W    = (size_t)DD * DD * 2;

constexpr size_t O_VT   = 0;
constexpr size_t O_ATTN = O_VT + SZ_VT;
constexpr size_t O_QH   = O_ATTN;
constexpr size_t O_QL   = O_QH + SZ_QK;
constexpr size_t O_KH   = O_QL + SZ_QK;
constexpr size_t O_KL   = O_KH + SZ_QK;
constexpr size_t O_S    = O_ATTN + SZ_ATTN;
constexpr size_t O_XH   = O_S;
constexpr size_t O_XL   = O_XH + SZ_QK;
constexpr size_t O_WQH  = O_XL + SZ_QK;
constexpr size_t O_WQL  = O_WQH + SZ_W;
constexpr size_t O_WKH  = O_WQL + SZ_W;
constexpr size_t O_WKL  = O_WKH + SZ_W;
constexpr size_t O_WVH  = O_WKL + SZ_W;
constexpr size_t O_WVL  = O_WVH + SZ_W;
constexpr size_t WS_NEEDED = SZ_VT + SZ_ATTN + SZ_S;

// ---------------- helpers ----------------
DEVFN f32x4 mfma16x16x32(bf16x8 a, bf16x8 b, f32x4 c) {
  return __builtin_amdgcn_mfma_f32_16x16x32_bf16(a, b, c, 0, 0, 0);
}

DEVFN void gld16(const __bf16* g, char* l) {
  __builtin_amdgcn_global_load_lds((const __attribute__((address_space(1))) void*)g,
                                   (__attribute__((address_space(3))) void*)l, 16, 0, 0);
}

// bijective XCD-chunked block swizzle (requires total blocks % 8 == 0)
DEVFN void swz_xy(int& bx, int& by, int& bz) {
  const int gx = gridDim.x, gy = gridDim.y, gz = gridDim.z;
  const int lin = (blockIdx.z * gy + blockIdx.y) * gx + blockIdx.x;
  const int chunk = (gx * gy * gz) >> 3;
  const int nl = (lin & 7) * chunk + (lin >> 3);
  bx = nl % gx; const int r = nl / gx; by = r % gy; bz = r / gy;
}

// =====================================================================
// 256x256 8-phase GEMM core, read-one-phase-ahead pipeline.
// Reads:  ph0: b1(cur) | ph1: a1(cur) | ph2: b0'(nxt) | ph3: a0'(nxt)
// MFMA:   ph0: a0*b0   | ph1: a0*b1   | ph2: a1*b0    | ph3: a1*b1
// Stages: ph0: A(u+1)q0,q2 | ph1: A(u+1)q1,q3 | ph2: B(u+2)q0,q1 | ph3: B(u+2)q2,q3
// Gate:   vmcnt(4) every phase end; lgkmcnt(R_phase) before MFMA.
// Per-wave B access touches only quarter wn; A-half a0 = quarters {0,2},
// a1 = {1,3}. All stage->read covers >= 2.2 phases.
// =====================================================================
struct Segs { const __bf16 *a0, *a1, *a2, *b0, *b1, *b2; };

DEVFN void gemm256_core(Segs s, int NT, char* smem, f32x4 (&acc)[8][4]) {
  const int tid = threadIdx.x, lane = tid & 63, wave = tid >> 6;
  const int wm = wave >> 2, wn = wave & 3;
  const size_t rk = (size_t)((wave << 3) + (lane >> 3)) * DD +
                    (size_t)((((lane & 7) ^ (lane >> 3)) << 3));
  const int wvoff = wave << 10;
  const int rbA = (((wm << 7) + (lane & 15)) << 7);
  const int rbB = (((wn << 6) + (lane & 15)) << 7);
  const int cx0 = (((lane >> 4) << 4)) ^ ((lane & 7) << 4);
  const int cx1 = cx0 ^ 64;

  char* LA0 = smem;
  char* LB0 = smem + 32768;
  char* LA1 = smem + 65536;
  char* LB1 = smem + 98304;

  auto stA = [&](int u, int q, char* dst) {
    int uc = (u < NT) ? u : (NT - 1);
    int sg = uc >> 4;
    const __bf16* p = (sg == 0) ? s.a0 : ((sg == 1) ? s.a1 : s.a2);
    gld16(p + ((size_t)(q << 6)) * DD + ((uc & 15) << 6) + rk, dst + (q << 13) + wvoff);
  };
  auto stB = [&](int u, int q, char* dst) {
    int uc = (u < NT) ? u : (NT - 1);
    int sg = uc >> 4;
    const __bf16* p = (sg == 0) ? s.b0 : ((sg == 1) ? s.b1 : s.b2);
    gld16(p + ((size_t)(q << 6)) * DD + ((uc & 15) << 6) + rk, dst + (q << 13) + wvoff);
  };
  auto rdA = [&](char* l, int m, int cx) { return *(const bf16x8*)(l + rbA + (m << 11) + cx); };
  auto rdB = [&](char* l, int n, int cx) { return *(const bf16x8*)(l + rbB + (n << 11) + cx); };

  bf16x8 A0[4][2], B0[2][2], A0n[4][2], B0n[2][2];

  // ---- prologue: 12 stages, keep newest 6 in flight ----
  stB(0, 0, LB0); stB(0, 1, LB0);
  stB(0, 2, LB0); stB(0, 3, LB0);
  stA(0, 0, LA0); stA(0, 2, LA0);
  stA(0, 1, LA0); stA(0, 3, LA0);
  stB(1, 0, LB1); stB(1, 1, LB1);
  stB(1, 2, LB1); stB(1, 3, LB1);
  asm volatile("s_waitcnt vmcnt(6)" ::: "memory");
  __builtin_amdgcn_s_barrier();
#pragma unroll
  for (int n = 0; n < 2; ++n) { B0[n][0] = rdB(LB0, n, cx0); B0[n][1] = rdB(LB0, n, cx1); }
#pragma unroll
  for (int m = 0; m < 4; ++m) { A0[m][0] = rdA(LA0, m, cx0); A0[m][1] = rdA(LA0, m, cx1); }

  auto tile = [&](char* lA, char* lB, char* lAn, char* lBn, int t,
                  bf16x8 (&a0)[4][2], bf16x8 (&b0)[2][2],
                  bf16x8 (&a0n)[4][2], bf16x8 (&b0n)[2][2]) {
    bf16x8 a1[4][2], b1[2][2];
    // ---- phase 0: read b1(cur); stage A(t+1)q0,q2; MFMA a0*b0 ----
#pragma unroll
    for (int n = 0; n < 2; ++n) { b1[n][0] = rdB(lB, n + 2, cx0); b1[n][1] = rdB(lB, n + 2, cx1); }
    stA(t + 1, 0, lAn); stA(t + 1, 2, lAn);
    asm volatile("s_waitcnt vmcnt(4)" ::: "memory");
    __builtin_amdgcn_s_barrier();
    asm volatile("s_waitcnt lgkmcnt(4)" ::: "memory");
    __builtin_amdgcn_sched_barrier(0);
    __builtin_amdgcn_s_setprio(1);
#pragma unroll
    for (int m = 0; m < 4; ++m)
#pragma unroll
      for (int n = 0; n < 2; ++n) {
        acc[m][n] = mfma16x16x32(a0[m][0], b0[n][0], acc[m][n]);
        acc[m][n] = mfma16x16x32(a0[m][1], b0[n][1], acc[m][n]);
      }
    __builtin_amdgcn_s_setprio(0);
    __builtin_amdgcn_s_barrier();
    // ---- phase 1: read a1(cur); stage A(t+1)q1,q3; MFMA a0*b1 ----
#pragma unroll
    for (int m = 0; m < 4; ++m) { a1[m][0] = rdA(lA, m + 4, cx0); a1[m][1] = rdA(lA, m + 4, cx1); }
    stA(t + 1, 1, lAn); stA(t + 1, 3, lAn);
    asm volatile("s_waitcnt vmcnt(4)" ::: "memory");
    __builtin_amdgcn_s_barrier();
    asm volatile("s_waitcnt lgkmcnt(8)" ::: "memory");
    __builtin_amdgcn_sched_barrier(0);
    __builtin_amdgcn_s_setprio(1);
#pragma unroll
    for (int m = 0; m < 4; ++m)
#pragma unroll
      for (int n = 0; n < 2; ++n) {
        acc[m][n + 2] = mfma16x16x32(a0[m][0], b1[n][0], acc[m][n + 2]);
        acc[m][n + 2] = mfma16x16x32(a0[m][1], b1[n][1], acc[m][n + 2]);
      }
    __builtin_amdgcn_s_setprio(0);
    __builtin_amdgcn_s_barrier();
    // ---- phase 2: read b0'(nxt); stage B(t+2)q0,q1 -> lB; MFMA a1*b0 ----
#pragma unroll
    for (int n = 0; n < 2; ++n) { b0n[n][0] = rdB(lBn, n, cx0); b0n[n][1] = rdB(lBn, n, cx1); }
    stB(t + 2, 0, lB); stB(t + 2, 1, lB);
    asm volatile("s_waitcnt vmcnt(4)" ::: "memory");
    __builtin_amdgcn_s_barrier();
    asm volatile("s_waitcnt lgkmcnt(4)" ::: "memory");
    __builtin_amdgcn_sched_barrier(0);
    __builtin_amdgcn_s_setprio(1);
#pragma unroll
    for (int m = 0; m < 4; ++m)
#pragma unroll
      for (int n = 0; n < 2; ++n) {
        acc[m + 4][n] = mfma16x16x32(a1[m][0], b0[n][0], acc[m + 4][n]);
        acc[m + 4][n] = mfma16x16x32(a1[m][1], b0[n][1], acc[m + 4][n]);
      }
    __builtin_amdgcn_s_setprio(0);
    __builtin_amdgcn_s_barrier();
    // ---- phase 3: read a0'(nxt); stage B(t+2)q2,q3 -> lB; MFMA a1*b1 ----
#pragma unroll
    for (int m = 0; m < 4; ++m) { a0n[m][0] = rdA(lAn, m, cx0); a0n[m][1] = rdA(lAn, m, cx1); }
    stB(t + 2, 2, lB); stB(t + 2, 3, lB);
    asm volatile("s_waitcnt vmcnt(4)" ::: "memory");
    __builtin_amdgcn_s_barrier();
    asm volatile("s_waitcnt lgkmcnt(8)" ::: "memory");
    __builtin_amdgcn_sched_barrier(0);
    __builtin_amdgcn_s_setprio(1);
#pragma unroll
    for (int m = 0; m < 4; ++m)
#pragma unroll
      for (int n = 0; n < 2; ++n) {
        acc[m + 4][n + 2] = mfma16x16x32(a1[m][0], b1[n][0], acc[m + 4][n + 2]);
        acc[m + 4][n + 2] = mfma16x16x32(a1[m][1], b1[n][1], acc[m + 4][n + 2]);
      }
    __builtin_amdgcn_s_setprio(0);
    __builtin_amdgcn_s_barrier();
  };

  for (int t = 0; t < NT; t += 2) {
    tile(LA0, LB0, LA1, LB1, t,     A0,  B0,  A0n, B0n);
    tile(LA1, LB1, LA0, LB0, t + 1, A0n, B0n, A0,  B0);
  }
  asm volatile("s_waitcnt vmcnt(0)" ::: "memory");
}

// ---------------- scores = [Qh|Qh|Ql] . [Kh|Kl|Kh]^T, fp32 out ----------------
__global__ __launch_bounds__(512, 2)
void gemm256_scores(const __bf16* __restrict__ Qh, const __bf16* __restrict__ Ql,
                    const __bf16* __restrict__ Kh, const __bf16* __restrict__ Kl,
                    float* __restrict__ Sf) {
  extern __shared__ char smem[];
  int bx, by, bz; swz_xy(bx, by, bz);
  const size_t zo = (size_t)bz * SS * DD;
  const int row0 = by * 256, col0 = bx * 256;
  const size_t ra = zo + (size_t)row0 * DD, rb = zo + (size_t)col0 * DD;
  Segs s{Qh + ra, Qh + ra, Ql + ra, Kh + rb, Kl + rb, Kh + rb};
  f32x4 acc[8][4] = {};
  gemm256_core(s, 48, smem, acc);

  float* C = Sf + (size_t)bz * SS * SS;
  const int lane = threadIdx.x & 63, wave = threadIdx.x >> 6;
  const int wm = wave >> 2, wn = wave & 3;
#pragma unroll
  for (int m = 0; m < 8; ++m)
#pragma unroll
    for (int n = 0; n < 4; ++n) {
      int col = col0 + wn * 64 + n * 16 + (lane & 15);
      int rowb = row0 + wm * 128 + m * 16 + (lane >> 4) * 4;
#pragma unroll
      for (int j = 0; j < 4; ++j)
        C[(size_t)(rowb + j) * SS + col] = acc[m][n][j];
    }
}

// ---------------- fused Q+K projections, N-concat (grid 8x32 = 256 blocks) -------
__global__ __launch_bounds__(512, 2)
void gemm256_projqk(const __bf16* __restrict__ xh, const __bf16* __restrict__ xl,
                    const __bf16* __restrict__ wqh, const __bf16* __restrict__ wql,
                    const __bf16* __restrict__ wkh, const __bf16* __restrict__ wkl,
                    const float* __restrict__ bq, const float* __restrict__ bk,
                    __bf16* __restrict__ Qh, __bf16* __restrict__ Ql,
                    __bf16* __restrict__ Kh, __bf16* __restrict__ Kl) {
  extern __shared__ char smem[];
  int bx, by, bz; swz_xy(bx, by, bz);
  const int row0 = by * 256;
  const int cg = bx;                  // 0..3 = Q cols, 4..7 = K cols
  const bool isK = cg >= 4;
  const int col0 = (cg & 3) * 256;
  const __bf16* B0p = isK ? wkh : wqh;
  const __bf16* B1p = isK ? wkl : wql;
  const float* bias = isK ? bk : bq;
  __bf16* CH = isK ? Kh : Qh;
  __bf16* CL = isK ? Kl : Ql;

  const size_t ra = (size_t)row0 * DD, rb = (size_t)col0 * DD;
  Segs s{xh + ra, xh + ra, xl + ra, B0p + rb, B1p + rb, B0p + rb};
  f32x4 acc[8][4] = {};
  gemm256_core(s, 48, smem, acc);

  const int lane = threadIdx.x & 63, wave = threadIdx.x >> 6;
  const int wm = wave >> 2, wn = wave & 3;
#pragma unroll
  for (int m = 0; m < 8; ++m)
#pragma unroll
    for (int n = 0; n < 4; ++n) {
      int col = col0 + wn * 64 + n * 16 + (lane & 15);
      float bvv = bias[col];
      int rowb = row0 + wm * 128 + m * 16 + (lane >> 4) * 4;
#pragma unroll
      for (int j = 0; j < 4; ++j) {
        float v = acc[m][n][j] + bvv;
        size_t idx = (size_t)(rowb + j) * DD + col;
        __bf16 h = (__bf16)v;
        CH[idx] = h;
        CL[idx] = (__bf16)(v - (float)h);
      }
    }
}

// ---------------- Vt = Wv . x^T directly (A=Wv [1024][1024], B=xh [8192][1024]) ---
__global__ __launch_bounds__(512, 2)
void gemm256_vt(const __bf16* __restrict__ wvh, const __bf16* __restrict__ xh,
                const float* __restrict__ bvv, __bf16* __restrict__ Vt) {
  extern __shared__ char smem[];
  int bx, by, bz; swz_xy(bx, by, bz);
  const int row0 = by * 256;  // d
  const int col0 = bx * 256;  // s global (0..8191)
  const size_t ra = (size_t)row0 * DD, rb = (size_t)col0 * DD;
  Segs s{wvh + ra, wvh + ra, wvh + ra, xh + rb, xh + rb, xh + rb};
  f32x4 acc[8][4] = {};
  gemm256_core(s, 16, smem, acc); // single segment, K=1024

  const int lane = threadIdx.x & 63, wave = threadIdx.x >> 6;
  const int wm = wave >> 2, wn = wave & 3;
#pragma unroll
  for (int m = 0; m < 8; ++m)
#pragma unroll
    for (int n = 0; n < 4; ++n) {
      int col = col0 + wn * 64 + n * 16 + (lane & 15);
      int batch = col >> 12, sl = col & 4095;
      int rowb = row0 + wm * 128 + m * 16 + (lane >> 4) * 4;
#pragma unroll
      for (int j = 0; j < 4; ++j) {
        float v = acc[m][n][j] + bvv[rowb + j]; // bias along d (rows)
        Vt[(size_t)batch * DD * SS + (size_t)(rowb + j) * SS + sl] = (__bf16)v;
      }
    }
}

// ---------------- split fp32 -> bf16 hi/lo ----------------
__global__ __launch_bounds__(256)
void split_f32_bf16x2(const float* __restrict__ in, __bf16* __restrict__ hi,
                      __bf16* __restrict__ lo, int n) {
  int stride = gridDim.x * blockDim.x;
  for (int i = blockIdx.x * blockDim.x + threadIdx.x; i * 4 < n; i += stride) {
    f32x4 x = *(const f32x4*)(in + (size_t)i * 4);
    bf16x4 h, l;
#pragma unroll
    for (int e = 0; e < 4; ++e) {
      __bf16 hh = (__bf16)x[e];
      h[e] = hh;
      l[e] = (__bf16)(x[e] - (float)hh);
    }
    *(bf16x4*)(hi + (size_t)i * 4) = h;
    *(bf16x4*)(lo + (size_t)i * 4) = l;
  }
}

// ---------------- legacy 128^2 GEMM for PV ----------------
DEVFN void stage_tile(__bf16* ldsb, const __bf16* gptr, int ld, int tid) {
  char* lb = (char*)ldsb + ((tid >> 6) << 10);
  gld16(gptr, lb);
  gld16(gptr + (size_t)64 * ld, lb + 4096);
}

__global__ __launch_bounds__(256)
void gemm_bt_pv(const __bf16* __restrict__ Ah, const __bf16* __restrict__ Bh,
                float* __restrict__ Cf, int M, int N, int K,
                size_t sAb, size_t sBb, size_t sCb) {
  const int b = blockIdx.z;
  Ah += (size_t)b * sAb; Bh += (size_t)b * sBb;

  __shared__ __bf16 lds[2][128 * 32];

  const int tid = threadIdx.x;
  const int lane = tid & 63, wave = tid >> 6;
  const int wm = (wave >> 1) * 64, wn = (wave & 1) * 64;
  const int row0 = blockIdx.y * 128, col0 = blockIdx.x * 128;
  const int sr = tid >> 2, sc = (tid & 3) * 8;

  const __bf16* gA = Ah + (size_t)(row0 + sr) * K + sc;
  const __bf16* gB = Bh + (size_t)(col0 + sr) * K + sc;

  f32x4 acc[4][4] = {};

  for (int k0 = 0; k0 < K; k0 += 32) {
    __syncthreads();
    stage_tile(lds[0], gA + k0, K, tid);
    stage_tile(lds[1], gB + k0, K, tid);
    __syncthreads();

    const int kg = (lane >> 4) * 8;
    bf16x8 ah[4], bh[4];
#pragma unroll
    for (int m = 0; m < 4; ++m)
      ah[m] = *(const bf16x8*)&lds[0][(wm + m * 16 + (lane & 15)) * 32 + kg];
#pragma unroll
    for (int n = 0; n < 4; ++n)
      bh[n] = *(const bf16x8*)&lds[1][(wn + n * 16 + (lane & 15)) * 32 + kg];
#pragma unroll
    for (int m = 0; m < 4; ++m)
#pragma unroll
      for (int n = 0; n < 4; ++n)
        acc[m][n] = mfma16x16x32(ah[m], bh[n], acc[m][n]);
  }

  Cf += (size_t)b * sCb;
#pragma unroll
  for (int m = 0; m < 4; ++m)
#pragma unroll
    for (int n = 0; n < 4; ++n) {
      int gcol = col0 + wn + n * 16 + (lane & 15);
#pragma unroll
      for (int j = 0; j < 4; ++j) {
        int grow = row0 + wm + m * 16 + (lane >> 4) * 4 + j;
        Cf[(size_t)grow * N + gcol] = acc[m][n][j];
      }
    }
}

// ---------------- softmax + dropout ----------------
__global__ __launch_bounds__(256)
void softmax_dropout(const float* __restrict__ Sf, const float* __restrict__ U,
                     __bf16* __restrict__ P) {
  __shared__ float red[4];
  const size_t row = blockIdx.x;
  const float* s = Sf + row * SS;
  const float* u = U + row * SS;
  __bf16* p = P + row * SS;
  const int tid = threadIdx.x, lane = tid & 63, wave = tid >> 6;

  f32x4 v[4];
  float m = -3.0e38f;
#pragma unroll
  for (int j = 0; j < 4; ++j) {
    v[j] = *(const f32x4*)(s + (size_t)(j * 256 + tid) * 4);
#pragma unroll
    for (int e = 0; e < 4; ++e) m = fmaxf(m, v[j][e]);
  }
#pragma unroll
  for (int o = 32; o > 0; o >>= 1) m = fmaxf(m, __shfl_xor(m, o));
  if (lane == 0) red[wave] = m;
  __syncthreads();
  m = fmaxf(fmaxf(red[0], red[1]), fmaxf(red[2], red[3]));

  float sum = 0.0f;
#pragma unroll
  for (int j = 0; j < 4; ++j)
#pragma unroll
    for (int e = 0; e < 4; ++e) { float ex = __expf(v[j][e] - m); v[j][e] = ex; sum += ex; }
#pragma unroll
  for (int o = 32; o > 0; o >>= 1) sum += __shfl_xor(sum, o);
  __syncthreads();
  if (lane == 0) red[wave] = sum;
  __syncthreads();
  sum = red[0] + red[1] + red[2] + red[3];
  const float scale = 1.25f / sum;

#pragma unroll
  for (int j = 0; j < 4; ++j) {
    f32x4 uu = *(const f32x4*)(u + (size_t)(j * 256 + tid) * 4);
    bf16x4 out;
#pragma unroll
    for (int e = 0; e < 4; ++e)
      out[e] = (__bf16)((uu[e] >= 0.2f) ? v[j][e] * scale : 0.0f);
    *(bf16x4*)(p + (size_t)(j * 256 + tid) * 4) = out;
  }
}

// ---------------- launcher ----------------
extern "C" void kernel_launch(void* const* d_in, const int* in_sizes, int n_in,
                              void* d_out, int out_size, void* d_ws, size_t ws_size,
                              hipStream_t stream) {
  if (ws_size < WS_NEEDED) return;

  const float* x  = (const float*)d_in[0];
  const float* Wq = (const float*)d_in[1];
  const float* bq = (const float*)d_in[2];
  const float* Wk = (const float*)d_in[3];
  const float* bk = (const float*)d_in[4];
  const float* Wv = (const float*)d_in[5];
  const float* bv = (const float*)d_in[6];
  const float* du = (const float*)d_in[7];

  char* ws = (char*)d_ws;
  __bf16* Vt  = (__bf16*)(ws + O_VT);
  __bf16* Pb  = (__bf16*)(ws + O_ATTN);
  __bf16* Qh  = (__bf16*)(ws + O_QH);
  __bf16* Ql  = (__bf16*)(ws + O_QL);
  __bf16* Kh  = (__bf16*)(ws + O_KH);
  __bf16* Kl  = (__bf16*)(ws + O_KL);
  float*  Sf  = (float*) (ws + O_S);
  __bf16* xh  = (__bf16*)(ws + O_XH);
  __bf16* xl  = (__bf16*)(ws + O_XL);
  __bf16* wqh = (__bf16*)(ws + O_WQH);
  __bf16* wql = (__bf16*)(ws + O_WQL);
  __bf16* wkh = (__bf16*)(ws + O_WKH);
  __bf16* wkl = (__bf16*)(ws + O_WKL);
  __bf16* wvh = (__bf16*)(ws + O_WVH);
  __bf16* wvl = (__bf16*)(ws + O_WVL);
  float*  out = (float*)d_out;

  hipFuncSetAttribute((const void*)gemm256_scores,
                      hipFuncAttributeMaxDynamicSharedMemorySize, 131072);
  hipFuncSetAttribute((const void*)gemm256_projqk,
                      hipFuncAttributeMaxDynamicSharedMemorySize, 131072);
  hipFuncSetAttribute((const void*)gemm256_vt,
                      hipFuncAttributeMaxDynamicSharedMemorySize, 131072);

  // 1) splits
  split_f32_bf16x2<<<2048, 256, 0, stream>>>(x,  xh,  xl,  MROWS * DD);
  split_f32_bf16x2<<<256,  256, 0, stream>>>(Wq, wqh, wql, DD * DD);
  split_f32_bf16x2<<<256,  256, 0, stream>>>(Wk, wkh, wkl, DD * DD);
  split_f32_bf16x2<<<256,  256, 0, stream>>>(Wv, wvh, wvl, DD * DD);

  // 2) Q+K projections, N-concat (256 blocks = 1/CU)
  gemm256_projqk<<<dim3(8, MROWS / 256), 512, 131072, stream>>>(
      xh, xl, wqh, wql, wkh, wkl, bq, bk, Qh, Ql, Kh, Kl);

  // 3) Vt = Wv . x^T + bv (direct transposed V)
  gemm256_vt<<<dim3(MROWS / 256, DD / 256), 512, 131072, stream>>>(wvh, xh, bv, Vt);

  // 4) scores = Q K^T (split via K-concat, fp32 out)
  gemm256_scores<<<dim3(SS / 256, SS / 256, BB), 512, 131072, stream>>>(Qh, Ql, Kh, Kl, Sf);

  // 5) softmax + dropout -> attn bf16 (overwrites dead Q/K splits)
  softmax_dropout<<<MROWS, 256, 0, stream>>>(Sf, du, Pb);

  // 6) out = attn @ V (B operand = Vt, K-contiguous)
  gemm_bt_pv<<<dim3(DD / 128, SS / 128, BB), 256, 0, stream>>>(
      Pb, Vt, out, SS, DD, SS,
      (size_t)SS * SS, (size_t)DD * SS, (size_t)SS * DD);
}

// Round 5
// 418.517 us; speedup vs baseline: 1.2662x; 1.2640x over previous
//
#include <hip/hip_runtime.h>

typedef float  f32x4  __attribute__((ext_vector_type(4)));
typedef __bf16 bf16x8 __attribute__((ext_vector_type(8)));
typedef __bf16 bf16x4 __attribute__((ext_vector_type(4)));

#define DEVFN static __device__ __forceinline__

constexpr int BB = 2, SS = 4096, DD = 1024;
constexpr int MROWS = BB * SS; // 8192

// ---------------- workspace layout (bytes) ----------------
constexpr size_t SZ_QK   = (size_t)MROWS * DD * 2;
constexpr size_t SZ_VT   = (size_t)BB * DD * SS * 2;
constexpr size_t SZ_ATTN = (size_t)BB * SS * SS * 2;
constexpr size_t SZ_S    = (size_t)BB * SS * SS * 4;
constexpr size_t SZ_W    = (size_t)DD * DD * 2;

constexpr size_t O_VT   = 0;
constexpr size_t O_ATTN = O_VT + SZ_VT;
constexpr size_t O_QH   = O_ATTN;
constexpr size_t O_QL   = O_QH + SZ_QK;
constexpr size_t O_KH   = O_QL + SZ_QK;
constexpr size_t O_KL   = O_KH + SZ_QK;
constexpr size_t O_S    = O_ATTN + SZ_ATTN;
constexpr size_t O_XH   = O_S;
constexpr size_t O_XL   = O_XH + SZ_QK;
constexpr size_t O_WQH  = O_XL + SZ_QK;
constexpr size_t O_WQL  = O_WQH + SZ_W;
constexpr size_t O_WKH  = O_WQL + SZ_W;
constexpr size_t O_WKL  = O_WKH + SZ_W;
constexpr size_t O_WVH  = O_WKL + SZ_W;
constexpr size_t O_WVL  = O_WVH + SZ_W;
constexpr size_t WS_NEEDED = SZ_VT + SZ_ATTN + SZ_S;

// ---------------- helpers ----------------
DEVFN f32x4 mfma16x16x32(bf16x8 a, bf16x8 b, f32x4 c) {
  return __builtin_amdgcn_mfma_f32_16x16x32_bf16(a, b, c, 0, 0, 0);
}

DEVFN void gld16(const __bf16* g, char* l) {
  __builtin_amdgcn_global_load_lds((const __attribute__((address_space(1))) void*)g,
                                   (__attribute__((address_space(3))) void*)l, 16, 0, 0);
}

// bijective XCD-chunked block swizzle (requires total blocks % 8 == 0)
DEVFN void swz_xy(int& bx, int& by, int& bz) {
  const int gx = gridDim.x, gy = gridDim.y, gz = gridDim.z;
  const int lin = (blockIdx.z * gy + blockIdx.y) * gx + blockIdx.x;
  const int chunk = (gx * gy * gz) >> 3;
  const int nl = (lin & 7) * chunk + (lin >> 3);
  bx = nl % gx; const int r = nl / gx; by = r % gy; bz = r / gy;
}

// =====================================================================
// 256x256 8-phase GEMM core (unchanged from R4; 48% MfmaUtil plateau)
// =====================================================================
struct Segs { const __bf16 *a0, *a1, *a2, *b0, *b1, *b2; };

DEVFN void gemm256_core(Segs s, int NT, char* smem, f32x4 (&acc)[8][4]) {
  const int tid = threadIdx.x, lane = tid & 63, wave = tid >> 6;
  const int wm = wave >> 2, wn = wave & 3;
  const size_t rk = (size_t)((wave << 3) + (lane >> 3)) * DD +
                    (size_t)((((lane & 7) ^ (lane >> 3)) << 3));
  const int wvoff = wave << 10;
  const int rbA = (((wm << 7) + (lane & 15)) << 7);
  const int rbB = (((wn << 6) + (lane & 15)) << 7);
  const int cx0 = (((lane >> 4) << 4)) ^ ((lane & 7) << 4);
  const int cx1 = cx0 ^ 64;

  char* LA0 = smem;
  char* LB0 = smem + 32768;
  char* LA1 = smem + 65536;
  char* LB1 = smem + 98304;

  auto stA = [&](int u, int q, char* dst) {
    int uc = (u < NT) ? u : (NT - 1);
    int sg = uc >> 4;
    const __bf16* p = (sg == 0) ? s.a0 : ((sg == 1) ? s.a1 : s.a2);
    gld16(p + ((size_t)(q << 6)) * DD + ((uc & 15) << 6) + rk, dst + (q << 13) + wvoff);
  };
  auto stB = [&](int u, int q, char* dst) {
    int uc = (u < NT) ? u : (NT - 1);
    int sg = uc >> 4;
    const __bf16* p = (sg == 0) ? s.b0 : ((sg == 1) ? s.b1 : s.b2);
    gld16(p + ((size_t)(q << 6)) * DD + ((uc & 15) << 6) + rk, dst + (q << 13) + wvoff);
  };
  auto rdA = [&](char* l, int m, int cx) { return *(const bf16x8*)(l + rbA + (m << 11) + cx); };
  auto rdB = [&](char* l, int n, int cx) { return *(const bf16x8*)(l + rbB + (n << 11) + cx); };

  bf16x8 A0[4][2], B0[2][2], A0n[4][2], B0n[2][2];

  stB(0, 0, LB0); stB(0, 1, LB0);
  stB(0, 2, LB0); stB(0, 3, LB0);
  stA(0, 0, LA0); stA(0, 2, LA0);
  stA(0, 1, LA0); stA(0, 3, LA0);
  stB(1, 0, LB1); stB(1, 1, LB1);
  stB(1, 2, LB1); stB(1, 3, LB1);
  asm volatile("s_waitcnt vmcnt(6)" ::: "memory");
  __builtin_amdgcn_s_barrier();
#pragma unroll
  for (int n = 0; n < 2; ++n) { B0[n][0] = rdB(LB0, n, cx0); B0[n][1] = rdB(LB0, n, cx1); }
#pragma unroll
  for (int m = 0; m < 4; ++m) { A0[m][0] = rdA(LA0, m, cx0); A0[m][1] = rdA(LA0, m, cx1); }

  auto tile = [&](char* lA, char* lB, char* lAn, char* lBn, int t,
                  bf16x8 (&a0)[4][2], bf16x8 (&b0)[2][2],
                  bf16x8 (&a0n)[4][2], bf16x8 (&b0n)[2][2]) {
    bf16x8 a1[4][2], b1[2][2];
    // ph0
#pragma unroll
    for (int n = 0; n < 2; ++n) { b1[n][0] = rdB(lB, n + 2, cx0); b1[n][1] = rdB(lB, n + 2, cx1); }
    stA(t + 1, 0, lAn); stA(t + 1, 2, lAn);
    asm volatile("s_waitcnt vmcnt(4)" ::: "memory");
    __builtin_amdgcn_s_barrier();
    asm volatile("s_waitcnt lgkmcnt(4)" ::: "memory");
    __builtin_amdgcn_sched_barrier(0);
    __builtin_amdgcn_s_setprio(1);
#pragma unroll
    for (int m = 0; m < 4; ++m)
#pragma unroll
      for (int n = 0; n < 2; ++n) {
        acc[m][n] = mfma16x16x32(a0[m][0], b0[n][0], acc[m][n]);
        acc[m][n] = mfma16x16x32(a0[m][1], b0[n][1], acc[m][n]);
      }
    __builtin_amdgcn_s_setprio(0);
    __builtin_amdgcn_s_barrier();
    // ph1
#pragma unroll
    for (int m = 0; m < 4; ++m) { a1[m][0] = rdA(lA, m + 4, cx0); a1[m][1] = rdA(lA, m + 4, cx1); }
    stA(t + 1, 1, lAn); stA(t + 1, 3, lAn);
    asm volatile("s_waitcnt vmcnt(4)" ::: "memory");
    __builtin_amdgcn_s_barrier();
    asm volatile("s_waitcnt lgkmcnt(8)" ::: "memory");
    __builtin_amdgcn_sched_barrier(0);
    __builtin_amdgcn_s_setprio(1);
#pragma unroll
    for (int m = 0; m < 4; ++m)
#pragma unroll
      for (int n = 0; n < 2; ++n) {
        acc[m][n + 2] = mfma16x16x32(a0[m][0], b1[n][0], acc[m][n + 2]);
        acc[m][n + 2] = mfma16x16x32(a0[m][1], b1[n][1], acc[m][n + 2]);
      }
    __builtin_amdgcn_s_setprio(0);
    __builtin_amdgcn_s_barrier();
    // ph2
#pragma unroll
    for (int n = 0; n < 2; ++n) { b0n[n][0] = rdB(lBn, n, cx0); b0n[n][1] = rdB(lBn, n, cx1); }
    stB(t + 2, 0, lB); stB(t + 2, 1, lB);
    asm volatile("s_waitcnt vmcnt(4)" ::: "memory");
    __builtin_amdgcn_s_barrier();
    asm volatile("s_waitcnt lgkmcnt(4)" ::: "memory");
    __builtin_amdgcn_sched_barrier(0);
    __builtin_amdgcn_s_setprio(1);
#pragma unroll
    for (int m = 0; m < 4; ++m)
#pragma unroll
      for (int n = 0; n < 2; ++n) {
        acc[m + 4][n] = mfma16x16x32(a1[m][0], b0[n][0], acc[m + 4][n]);
        acc[m + 4][n] = mfma16x16x32(a1[m][1], b0[n][1], acc[m + 4][n]);
      }
    __builtin_amdgcn_s_setprio(0);
    __builtin_amdgcn_s_barrier();
    // ph3
#pragma unroll
    for (int m = 0; m < 4; ++m) { a0n[m][0] = rdA(lAn, m, cx0); a0n[m][1] = rdA(lAn, m, cx1); }
    stB(t + 2, 2, lB); stB(t + 2, 3, lB);
    asm volatile("s_waitcnt vmcnt(4)" ::: "memory");
    __builtin_amdgcn_s_barrier();
    asm volatile("s_waitcnt lgkmcnt(8)" ::: "memory");
    __builtin_amdgcn_sched_barrier(0);
    __builtin_amdgcn_s_setprio(1);
#pragma unroll
    for (int m = 0; m < 4; ++m)
#pragma unroll
      for (int n = 0; n < 2; ++n) {
        acc[m + 4][n + 2] = mfma16x16x32(a1[m][0], b1[n][0], acc[m + 4][n + 2]);
        acc[m + 4][n + 2] = mfma16x16x32(a1[m][1], b1[n][1], acc[m + 4][n + 2]);
      }
    __builtin_amdgcn_s_setprio(0);
    __builtin_amdgcn_s_barrier();
  };

  for (int t = 0; t < NT; t += 2) {
    tile(LA0, LB0, LA1, LB1, t,     A0,  B0,  A0n, B0n);
    tile(LA1, LB1, LA0, LB0, t + 1, A0n, B0n, A0,  B0);
  }
  asm volatile("s_waitcnt vmcnt(0)" ::: "memory");
}

// =====================================================================
// 256x128 8-phase GEMM core (new). 8 waves as 4m x 2n, wave-tile 64x64.
// LDS 96 KiB: A 4x8KB quarters, B 2x8KB quarters, double-buffered.
// Stages: ph0: A(t+1)q01 | ph1: A(t+1)q23 | ph2: B(t+2)q01 | ph3: none
// Waits: vmcnt(4) @ph1-end (B(t+1) landed for ph2 read);
//        vmcnt(2) @ph2-end (A(t+1) all landed for ph3/next-tile reads).
// Ledger verified: every DMA->ds_read cover >= 2 phases; every buffer
// overwrite >= 2 barriers after last reader.
// =====================================================================
DEVFN void gemm128_core(const __bf16* Ap, const __bf16* Bp, size_t ld, int NT,
                        char* smem, f32x4 (&acc)[4][4]) {
  const int tid = threadIdx.x, lane = tid & 63, wave = tid >> 6;
  const int wm = wave >> 1, wn = wave & 1;
  const size_t rk = (size_t)(tid >> 3) * ld +
                    (size_t)((((lane & 7) ^ (lane >> 3)) << 3));
  const int wvoff = wave << 10;
  const int rbA = (((wm << 6) + (lane & 15)) << 7);
  const int rbB = (((wn << 6) + (lane & 15)) << 7);
  const int cx0 = (((lane >> 4) << 4)) ^ ((lane & 7) << 4);
  const int cx1 = cx0 ^ 64;

  char* LA0 = smem;            // 32KB
  char* LB0 = smem + 32768;    // 16KB
  char* LA1 = smem + 49152;    // 32KB
  char* LB1 = smem + 81920;    // 16KB

  auto stA = [&](int u, int q, char* dst) {
    int uc = (u < NT) ? u : (NT - 1);
    gld16(Ap + (size_t)(q << 6) * ld + ((size_t)uc << 6) + rk, dst + (q << 13) + wvoff);
  };
  auto stB = [&](int u, int q, char* dst) {
    int uc = (u < NT) ? u : (NT - 1);
    gld16(Bp + (size_t)(q << 6) * ld + ((size_t)uc << 6) + rk, dst + (q << 13) + wvoff);
  };
  auto rdA = [&](char* l, int m, int cx) { return *(const bf16x8*)(l + rbA + (m << 11) + cx); };
  auto rdB = [&](char* l, int n, int cx) { return *(const bf16x8*)(l + rbB + (n << 11) + cx); };

  bf16x8 A0[2][2], B0[2][2], A0n[2][2], B0n[2][2];

  // prologue: tile0 fully + B(1); keep B(1) in flight
  stA(0, 0, LA0); stA(0, 1, LA0); stA(0, 2, LA0); stA(0, 3, LA0);
  stB(0, 0, LB0); stB(0, 1, LB0);
  stB(1, 0, LB1); stB(1, 1, LB1);
  asm volatile("s_waitcnt vmcnt(2)" ::: "memory");
  __builtin_amdgcn_s_barrier();
#pragma unroll
  for (int n = 0; n < 2; ++n) { B0[n][0] = rdB(LB0, n, cx0); B0[n][1] = rdB(LB0, n, cx1); }
#pragma unroll
  for (int m = 0; m < 2; ++m) { A0[m][0] = rdA(LA0, m, cx0); A0[m][1] = rdA(LA0, m, cx1); }

  auto tile = [&](char* lA, char* lB, char* lAn, char* lBn, int t,
                  bf16x8 (&a0)[2][2], bf16x8 (&b0)[2][2],
                  bf16x8 (&a0n)[2][2], bf16x8 (&b0n)[2][2]) {
    bf16x8 a1[2][2], b1[2][2];
    // ---- ph0: read b1(cur); stage A(t+1)q0,q1; MFMA a0*b0 ----
#pragma unroll
    for (int n = 0; n < 2; ++n) { b1[n][0] = rdB(lB, n + 2, cx0); b1[n][1] = rdB(lB, n + 2, cx1); }
    stA(t + 1, 0, lAn); stA(t + 1, 1, lAn);
    __builtin_amdgcn_s_barrier();
    asm volatile("s_waitcnt lgkmcnt(4)" ::: "memory");
    __builtin_amdgcn_sched_barrier(0);
    __builtin_amdgcn_s_setprio(1);
#pragma unroll
    for (int m = 0; m < 2; ++m)
#pragma unroll
      for (int n = 0; n < 2; ++n) {
        acc[m][n] = mfma16x16x32(a0[m][0], b0[n][0], acc[m][n]);
        acc[m][n] = mfma16x16x32(a0[m][1], b0[n][1], acc[m][n]);
      }
    __builtin_amdgcn_s_setprio(0);
    __builtin_amdgcn_s_barrier();
    // ---- ph1: read a1(cur); stage A(t+1)q2,q3; MFMA a0*b1 ----
#pragma unroll
    for (int m = 0; m < 2; ++m) { a1[m][0] = rdA(lA, m + 2, cx0); a1[m][1] = rdA(lA, m + 2, cx1); }
    stA(t + 1, 2, lAn); stA(t + 1, 3, lAn);
    asm volatile("s_waitcnt vmcnt(4)" ::: "memory");
    __builtin_amdgcn_s_barrier();
    asm volatile("s_waitcnt lgkmcnt(4)" ::: "memory");
    __builtin_amdgcn_sched_barrier(0);
    __builtin_amdgcn_s_setprio(1);
#pragma unroll
    for (int m = 0; m < 2; ++m)
#pragma unroll
      for (int n = 0; n < 2; ++n) {
        acc[m][n + 2] = mfma16x16x32(a0[m][0], b1[n][0], acc[m][n + 2]);
        acc[m][n + 2] = mfma16x16x32(a0[m][1], b1[n][1], acc[m][n + 2]);
      }
    __builtin_amdgcn_s_setprio(0);
    __builtin_amdgcn_s_barrier();
    // ---- ph2: read b0'(nxt); stage B(t+2)q0,q1 -> lB; MFMA a1*b0 ----
#pragma unroll
    for (int n = 0; n < 2; ++n) { b0n[n][0] = rdB(lBn, n, cx0); b0n[n][1] = rdB(lBn, n, cx1); }
    stB(t + 2, 0, lB); stB(t + 2, 1, lB);
    asm volatile("s_waitcnt vmcnt(2)" ::: "memory");
    __builtin_amdgcn_s_barrier();
    asm volatile("s_waitcnt lgkmcnt(4)" ::: "memory");
    __builtin_amdgcn_sched_barrier(0);
    __builtin_amdgcn_s_setprio(1);
#pragma unroll
    for (int m = 0; m < 2; ++m)
#pragma unroll
      for (int n = 0; n < 2; ++n) {
        acc[m + 2][n] = mfma16x16x32(a1[m][0], b0[n][0], acc[m + 2][n]);
        acc[m + 2][n] = mfma16x16x32(a1[m][1], b0[n][1], acc[m + 2][n]);
      }
    __builtin_amdgcn_s_setprio(0);
    __builtin_amdgcn_s_barrier();
    // ---- ph3: read a0'(nxt); MFMA a1*b1 ----
#pragma unroll
    for (int m = 0; m < 2; ++m) { a0n[m][0] = rdA(lAn, m, cx0); a0n[m][1] = rdA(lAn, m, cx1); }
    __builtin_amdgcn_s_barrier();
    asm volatile("s_waitcnt lgkmcnt(4)" ::: "memory");
    __builtin_amdgcn_sched_barrier(0);
    __builtin_amdgcn_s_setprio(1);
#pragma unroll
    for (int m = 0; m < 2; ++m)
#pragma unroll
      for (int n = 0; n < 2; ++n) {
        acc[m + 2][n + 2] = mfma16x16x32(a1[m][0], b1[n][0], acc[m + 2][n + 2]);
        acc[m + 2][n + 2] = mfma16x16x32(a1[m][1], b1[n][1], acc[m + 2][n + 2]);
      }
    __builtin_amdgcn_s_setprio(0);
    __builtin_amdgcn_s_barrier();
  };

  for (int t = 0; t < NT; t += 2) {
    tile(LA0, LB0, LA1, LB1, t,     A0, B0, A0n, B0n);
    tile(LA1, LB1, LA0, LB0, t + 1, A0n, B0n, A0, B0);
  }
  asm volatile("s_waitcnt vmcnt(0)" ::: "memory");
}

// ---------------- scores = [Qh|Qh|Ql] . [Kh|Kl|Kh]^T, fp32 out ----------------
__global__ __launch_bounds__(512, 2)
void gemm256_scores(const __bf16* __restrict__ Qh, const __bf16* __restrict__ Ql,
                    const __bf16* __restrict__ Kh, const __bf16* __restrict__ Kl,
                    float* __restrict__ Sf) {
  extern __shared__ char smem[];
  int bx, by, bz; swz_xy(bx, by, bz);
  const size_t zo = (size_t)bz * SS * DD;
  const int row0 = by * 256, col0 = bx * 256;
  const size_t ra = zo + (size_t)row0 * DD, rb = zo + (size_t)col0 * DD;
  Segs s{Qh + ra, Qh + ra, Ql + ra, Kh + rb, Kl + rb, Kh + rb};
  f32x4 acc[8][4] = {};
  gemm256_core(s, 48, smem, acc);

  float* C = Sf + (size_t)bz * SS * SS;
  const int lane = threadIdx.x & 63, wave = threadIdx.x >> 6;
  const int wm = wave >> 2, wn = wave & 3;
#pragma unroll
  for (int m = 0; m < 8; ++m)
#pragma unroll
    for (int n = 0; n < 4; ++n) {
      int col = col0 + wn * 64 + n * 16 + (lane & 15);
      int rowb = row0 + wm * 128 + m * 16 + (lane >> 4) * 4;
#pragma unroll
      for (int j = 0; j < 4; ++j)
        C[(size_t)(rowb + j) * SS + col] = acc[m][n][j];
    }
}

// ---------------- fused Q+K projections, N-concat (256 blocks) -------
__global__ __launch_bounds__(512, 2)
void gemm256_projqk(const __bf16* __restrict__ xh, const __bf16* __restrict__ xl,
                    const __bf16* __restrict__ wqh, const __bf16* __restrict__ wql,
                    const __bf16* __restrict__ wkh, const __bf16* __restrict__ wkl,
                    const float* __restrict__ bq, const float* __restrict__ bk,
                    __bf16* __restrict__ Qh, __bf16* __restrict__ Ql,
                    __bf16* __restrict__ Kh, __bf16* __restrict__ Kl) {
  extern __shared__ char smem[];
  int bx, by, bz; swz_xy(bx, by, bz);
  const int row0 = by * 256;
  const int cg = bx;
  const bool isK = cg >= 4;
  const int col0 = (cg & 3) * 256;
  const __bf16* B0p = isK ? wkh : wqh;
  const __bf16* B1p = isK ? wkl : wql;
  const float* bias = isK ? bk : bq;
  __bf16* CH = isK ? Kh : Qh;
  __bf16* CL = isK ? Kl : Ql;

  const size_t ra = (size_t)row0 * DD, rb = (size_t)col0 * DD;
  Segs s{xh + ra, xh + ra, xl + ra, B0p + rb, B1p + rb, B0p + rb};
  f32x4 acc[8][4] = {};
  gemm256_core(s, 48, smem, acc);

  const int lane = threadIdx.x & 63, wave = threadIdx.x >> 6;
  const int wm = wave >> 2, wn = wave & 3;
#pragma unroll
  for (int m = 0; m < 8; ++m)
#pragma unroll
    for (int n = 0; n < 4; ++n) {
      int col = col0 + wn * 64 + n * 16 + (lane & 15);
      float bvv = bias[col];
      int rowb = row0 + wm * 128 + m * 16 + (lane >> 4) * 4;
#pragma unroll
      for (int j = 0; j < 4; ++j) {
        float v = acc[m][n][j] + bvv;
        size_t idx = (size_t)(rowb + j) * DD + col;
        __bf16 h = (__bf16)v;
        CH[idx] = h;
        CL[idx] = (__bf16)(v - (float)h);
      }
    }
}

// ---------------- Vt = Wv . x^T (256x128 core, 256 blocks) ----------------
__global__ __launch_bounds__(512, 2)
void gemm_vt128(const __bf16* __restrict__ wvh, const __bf16* __restrict__ xh,
                const float* __restrict__ bvv, __bf16* __restrict__ Vt) {
  extern __shared__ char smem[];
  int bx, by, bz; swz_xy(bx, by, bz);
  const int row0 = by * 256;  // d
  const int col0 = bx * 128;  // s global (0..8191)
  f32x4 acc[4][4] = {};
  gemm128_core(wvh + (size_t)row0 * DD, xh + (size_t)col0 * DD, DD, 16, smem, acc);

  const int lane = threadIdx.x & 63, wave = threadIdx.x >> 6;
  const int wm = wave >> 1, wn = wave & 1;
#pragma unroll
  for (int m = 0; m < 4; ++m)
#pragma unroll
    for (int n = 0; n < 4; ++n) {
      int col = col0 + wn * 64 + n * 16 + (lane & 15);
      int batch = col >> 12, sl = col & 4095;
      int rowb = row0 + wm * 64 + m * 16 + (lane >> 4) * 4;
#pragma unroll
      for (int j = 0; j < 4; ++j) {
        float v = acc[m][n][j] + bvv[rowb + j];
        Vt[(size_t)batch * DD * SS + (size_t)(rowb + j) * SS + sl] = (__bf16)v;
      }
    }
}

// ---------------- out = attn @ V (256x128 core, 256 blocks) ----------------
__global__ __launch_bounds__(512, 2)
void gemm_pv128(const __bf16* __restrict__ Pb, const __bf16* __restrict__ Vt,
                float* __restrict__ out) {
  extern __shared__ char smem[];
  int bx, by, bz; swz_xy(bx, by, bz);
  const int row0 = by * 256;  // q
  const int col0 = bx * 128;  // d
  f32x4 acc[4][4] = {};
  gemm128_core(Pb + (size_t)bz * SS * SS + (size_t)row0 * SS,
               Vt + (size_t)bz * DD * SS + (size_t)col0 * SS,
               SS, 64, smem, acc);

  float* C = out + (size_t)bz * SS * DD;
  const int lane = threadIdx.x & 63, wave = threadIdx.x >> 6;
  const int wm = wave >> 1, wn = wave & 1;
#pragma unroll
  for (int m = 0; m < 4; ++m)
#pragma unroll
    for (int n = 0; n < 4; ++n) {
      int col = col0 + wn * 64 + n * 16 + (lane & 15);
      int rowb = row0 + wm * 64 + m * 16 + (lane >> 4) * 4;
#pragma unroll
      for (int j = 0; j < 4; ++j)
        C[(size_t)(rowb + j) * DD + col] = acc[m][n][j];
    }
}

// ---------------- fused splits: x, Wq, Wk, Wv in one dispatch ----------------
__global__ __launch_bounds__(256)
void split_all(const float* __restrict__ x, const float* __restrict__ Wq,
               const float* __restrict__ Wk, const float* __restrict__ Wv,
               __bf16* __restrict__ xh, __bf16* __restrict__ xl,
               __bf16* __restrict__ wqh, __bf16* __restrict__ wql,
               __bf16* __restrict__ wkh, __bf16* __restrict__ wkl,
               __bf16* __restrict__ wvh) {
  const int b = blockIdx.x, tid = threadIdx.x;
  const float* in; __bf16 *hi, *lo; int nv, rb, nb;
  if (b < 1536)      { in = x;  hi = xh;  lo = xl;  nv = (MROWS * DD) >> 2; rb = b;        nb = 1536; }
  else if (b < 1792) { in = Wq; hi = wqh; lo = wql; nv = (DD * DD) >> 2;    rb = b - 1536; nb = 256; }
  else if (b < 2048) { in = Wk; hi = wkh; lo = wkl; nv = (DD * DD) >> 2;    rb = b - 1792; nb = 256; }
  else               { in = Wv; hi = wvh; lo = nullptr; nv = (DD * DD) >> 2; rb = b - 2048; nb = 256; }
  for (int i = rb * 256 + tid; i < nv; i += nb * 256) {
    f32x4 v = *(const f32x4*)(in + (size_t)i * 4);
    bf16x4 h, l;
#pragma unroll
    for (int e = 0; e < 4; ++e) {
      __bf16 hh = (__bf16)v[e];
      h[e] = hh;
      l[e] = (__bf16)(v[e] - (float)hh);
    }
    *(bf16x4*)(hi + (size_t)i * 4) = h;
    if (lo) *(bf16x4*)(lo + (size_t)i * 4) = l;
  }
}

// ---------------- softmax + dropout ----------------
__global__ __launch_bounds__(256)
void softmax_dropout(const float* __restrict__ Sf, const float* __restrict__ U,
                     __bf16* __restrict__ P) {
  __shared__ float red[4];
  const size_t row = blockIdx.x;
  const float* s = Sf + row * SS;
  const float* u = U + row * SS;
  __bf16* p = P + row * SS;
  const int tid = threadIdx.x, lane = tid & 63, wave = tid >> 6;

  f32x4 v[4];
  float m = -3.0e38f;
#pragma unroll
  for (int j = 0; j < 4; ++j) {
    v[j] = *(const f32x4*)(s + (size_t)(j * 256 + tid) * 4);
#pragma unroll
    for (int e = 0; e < 4; ++e) m = fmaxf(m, v[j][e]);
  }
#pragma unroll
  for (int o = 32; o > 0; o >>= 1) m = fmaxf(m, __shfl_xor(m, o));
  if (lane == 0) red[wave] = m;
  __syncthreads();
  m = fmaxf(fmaxf(red[0], red[1]), fmaxf(red[2], red[3]));

  float sum = 0.0f;
#pragma unroll
  for (int j = 0; j < 4; ++j)
#pragma unroll
    for (int e = 0; e < 4; ++e) { float ex = __expf(v[j][e] - m); v[j][e] = ex; sum += ex; }
#pragma unroll
  for (int o = 32; o > 0; o >>= 1) sum += __shfl_xor(sum, o);
  __syncthreads();
  if (lane == 0) red[wave] = sum;
  __syncthreads();
  sum = red[0] + red[1] + red[2] + red[3];
  const float scale = 1.25f / sum;

#pragma unroll
  for (int j = 0; j < 4; ++j) {
    f32x4 uu = *(const f32x4*)(u + (size_t)(j * 256 + tid) * 4);
    bf16x4 out;
#pragma unroll
    for (int e = 0; e < 4; ++e)
      out[e] = (__bf16)((uu[e] >= 0.2f) ? v[j][e] * scale : 0.0f);
    *(bf16x4*)(p + (size_t)(j * 256 + tid) * 4) = out;
  }
}

// ---------------- launcher ----------------
extern "C" void kernel_launch(void* const* d_in, const int* in_sizes, int n_in,
                              void* d_out, int out_size, void* d_ws, size_t ws_size,
                              hipStream_t stream) {
  if (ws_size < WS_NEEDED) return;

  const float* x  = (const float*)d_in[0];
  const float* Wq = (const float*)d_in[1];
  const float* bq = (const float*)d_in[2];
  const float* Wk = (const float*)d_in[3];
  const float* bk = (const float*)d_in[4];
  const float* Wv = (const float*)d_in[5];
  const float* bv = (const float*)d_in[6];
  const float* du = (const float*)d_in[7];

  char* ws = (char*)d_ws;
  __bf16* Vt  = (__bf16*)(ws + O_VT);
  __bf16* Pb  = (__bf16*)(ws + O_ATTN);
  __bf16* Qh  = (__bf16*)(ws + O_QH);
  __bf16* Ql  = (__bf16*)(ws + O_QL);
  __bf16* Kh  = (__bf16*)(ws + O_KH);
  __bf16* Kl  = (__bf16*)(ws + O_KL);
  float*  Sf  = (float*) (ws + O_S);
  __bf16* xh  = (__bf16*)(ws + O_XH);
  __bf16* xl  = (__bf16*)(ws + O_XL);
  __bf16* wqh = (__bf16*)(ws + O_WQH);
  __bf16* wql = (__bf16*)(ws + O_WQL);
  __bf16* wkh = (__bf16*)(ws + O_WKH);
  __bf16* wkl = (__bf16*)(ws + O_WKL);
  __bf16* wvh = (__bf16*)(ws + O_WVH);
  float*  out = (float*)d_out;

  hipFuncSetAttribute((const void*)gemm256_scores,
                      hipFuncAttributeMaxDynamicSharedMemorySize, 131072);
  hipFuncSetAttribute((const void*)gemm256_projqk,
                      hipFuncAttributeMaxDynamicSharedMemorySize, 131072);
  hipFuncSetAttribute((const void*)gemm_vt128,
                      hipFuncAttributeMaxDynamicSharedMemorySize, 98304);
  hipFuncSetAttribute((const void*)gemm_pv128,
                      hipFuncAttributeMaxDynamicSharedMemorySize, 98304);

  // 1) splits (one dispatch)
  split_all<<<2304, 256, 0, stream>>>(x, Wq, Wk, Wv, xh, xl, wqh, wql, wkh, wkl, wvh);

  // 2) Q+K projections (256 blocks)
  gemm256_projqk<<<dim3(8, MROWS / 256), 512, 131072, stream>>>(
      xh, xl, wqh, wql, wkh, wkl, bq, bk, Qh, Ql, Kh, Kl);

  // 3) Vt = Wv . x^T + bv (256 blocks, new core)
  gemm_vt128<<<dim3(MROWS / 128, DD / 256), 512, 98304, stream>>>(wvh, xh, bv, Vt);

  // 4) scores = Q K^T (split via K-concat, fp32 out)
  gemm256_scores<<<dim3(SS / 256, SS / 256, BB), 512, 131072, stream>>>(Qh, Ql, Kh, Kl, Sf);

  // 5) softmax + dropout -> attn bf16
  softmax_dropout<<<MROWS, 256, 0, stream>>>(Sf, du, Pb);

  // 6) out = attn @ V (256 blocks, new core)
  gemm_pv128<<<dim3(DD / 128, SS / 256, BB), 512, 98304, stream>>>(Pb, Vt, out);
}